// Round 3
// baseline (341.814 us; speedup 1.0000x reference)
//
#include <hip/hip_runtime.h>
#include <math.h>

#define D 256
#define NX 16
#define L 2048
#define NBATCH 8
#define NTOK (NBATCH * L)
#define CL 32
#define NCH (L / CL)  // 64
#define LOG2E 1.44269504088896340736f

// ---------------- K1: wave-per-token front end ----------------
// h = y@Win + bin (regs); hn = LN(h); delta = softplus(pd + hn.qd); Bm; Cm
__global__ __launch_bounds__(256) void k1_front(
    const float* __restrict__ y, const float* __restrict__ Win,
    const float* __restrict__ bin_, const float* __restrict__ ng,
    const float* __restrict__ nb, const float* __restrict__ WB,
    const float* __restrict__ WC, const float* __restrict__ qd,
    const float* __restrict__ pd,
    float* __restrict__ hn, float* __restrict__ delta,
    float* __restrict__ Bm, float* __restrict__ Cm) {
  __shared__ float s_hn[4][D];
  int t = threadIdx.x;
  int w = t >> 6, lane = t & 63;
  int tok = blockIdx.x * 4 + w;
  float vy = y[tok * 32 + (lane & 31)];
  const float4* Win4 = (const float4*)Win;  // [p][64 float4]
  float4 acc = ((const float4*)bin_)[lane];
  #pragma unroll
  for (int p = 0; p < 32; ++p) {
    float yp = __shfl(vy, p);
    float4 wv = Win4[p * 64 + lane];
    acc.x = fmaf(yp, wv.x, acc.x);
    acc.y = fmaf(yp, wv.y, acc.y);
    acc.z = fmaf(yp, wv.z, acc.z);
    acc.w = fmaf(yp, wv.w, acc.w);
  }
  // layernorm over the wave (256 values, 4 per lane)
  float s1 = acc.x + acc.y + acc.z + acc.w;
  float s2 = acc.x * acc.x + acc.y * acc.y + acc.z * acc.z + acc.w * acc.w;
  #pragma unroll
  for (int off = 1; off < 64; off <<= 1) {
    s1 += __shfl_xor(s1, off);
    s2 += __shfl_xor(s2, off);
  }
  float mu = s1 * (1.f / D);
  float var = s2 * (1.f / D) - mu * mu;
  float rstd = rsqrtf(var + 1e-5f);
  float4 g4 = ((const float4*)ng)[lane];
  float4 b4 = ((const float4*)nb)[lane];
  float4 v4;
  v4.x = (acc.x - mu) * rstd * g4.x + b4.x;
  v4.y = (acc.y - mu) * rstd * g4.y + b4.y;
  v4.z = (acc.z - mu) * rstd * g4.z + b4.z;
  v4.w = (acc.w - mu) * rstd * g4.w + b4.w;
  ((float4*)(hn + (size_t)tok * D))[lane] = v4;
  *(float4*)&s_hn[w][lane * 4] = v4;
  // delta
  float4 q4 = ((const float4*)qd)[lane];
  float dd = v4.x * q4.x + v4.y * q4.y + v4.z * q4.z + v4.w * q4.w;
  #pragma unroll
  for (int off = 1; off < 64; off <<= 1) dd += __shfl_xor(dd, off);
  if (lane == 0) {
    float xx = pd[0] + dd;
    delta[tok] = (xx > 20.f) ? xx : log1pf(expf(xx));
  }
  // B/C projections: lane = (q,n), q=lane>>4 covers d in [q*64,q*64+64)
  int n = lane & 15, q = lane >> 4;
  const float4* wbr = (const float4*)(WB + n * D + q * 64);
  const float4* wcr = (const float4*)(WC + n * D + q * 64);
  const float4* hq = (const float4*)&s_hn[w][q * 64];
  float pB = 0.f, pC = 0.f;
  #pragma unroll
  for (int j = 0; j < 16; ++j) {
    float4 hv = hq[j];
    float4 wb = wbr[j];
    float4 wc = wcr[j];
    pB += hv.x * wb.x + hv.y * wb.y + hv.z * wb.z + hv.w * wb.w;
    pC += hv.x * wc.x + hv.y * wc.y + hv.z * wc.z + hv.w * wc.w;
  }
  pB += __shfl_xor(pB, 16); pB += __shfl_xor(pB, 32);
  pC += __shfl_xor(pC, 16); pC += __shfl_xor(pC, 32);
  if (lane < 16) Bm[tok * NX + lane] = pB;
  else if (lane < 32) Cm[tok * NX + (lane - 16)] = pC;
}

// ---------------- K2a: local chunk scans, thread = d, x[16] in regs --------
__global__ __launch_bounds__(256) void k2a_local(
    const float* __restrict__ hn, const float* __restrict__ delta,
    const float* __restrict__ Bm, const float* __restrict__ Cm,
    const float* __restrict__ A,
    float* __restrict__ ypart, float* __restrict__ EX,
    float* __restrict__ S, float* __restrict__ T) {
  __shared__ float sdelta[CL];
  __shared__ float sB[CL][NX];
  __shared__ float sC[CL][NX];
  __shared__ float shn[CL][D];  // 32 KB
  int blk = blockIdx.x;
  int ch = blk & (NCH - 1);
  int b = blk >> 6;
  int t = threadIdx.x;  // = d
  int l0 = ch * CL;
  if (t < CL) sdelta[t] = delta[b * L + l0 + t];
  for (int i = t; i < CL * NX; i += 256) {
    ((float*)sB)[i] = Bm[(size_t)(b * L + l0) * NX + i];
    ((float*)sC)[i] = Cm[(size_t)(b * L + l0) * NX + i];
  }
  {
    const float4* src = (const float4*)(hn + (size_t)(b * L + l0) * D);
    float4* dst = (float4*)shn;
    for (int i = t; i < CL * D / 4; i += 256) dst[i] = src[i];
  }
  __syncthreads();
  if (t < 32) {  // inclusive delta cumsum (CL = 32 lanes, all active)
    float v = sdelta[t];
    #pragma unroll
    for (int off = 1; off < 32; off <<= 1) {
      float u = __shfl_up(v, off);
      if (t >= off) v += u;
    }
    S[b * L + l0 + t] = v;
    if (t == 31) T[b * NCH + ch] = v;
  }
  float4 A2[4];
  {
    const float4* Arow = (const float4*)(A + t * NX);
    #pragma unroll
    for (int qq = 0; qq < 4; ++qq) {
      float4 a = Arow[qq];
      A2[qq] = make_float4(a.x * LOG2E, a.y * LOG2E, a.z * LOG2E, a.w * LOG2E);
    }
  }
  float x16[16];
  #pragma unroll
  for (int i = 0; i < 16; ++i) x16[i] = 0.f;
  for (int lo = 0; lo < CL; ++lo) {
    float dlt = sdelta[lo];
    float du = dlt * shn[lo][t];
    const float4* bp = (const float4*)sB[lo];
    const float4* cp = (const float4*)sC[lo];
    float p = 0.f;
    #pragma unroll
    for (int qq = 0; qq < 4; ++qq) {
      float4 bq = bp[qq], cq = cp[qq], aq = A2[qq];
      float da;
      da = exp2f(dlt * aq.x); x16[qq*4+0] = fmaf(da, x16[qq*4+0], du * bq.x); p = fmaf(x16[qq*4+0], cq.x, p);
      da = exp2f(dlt * aq.y); x16[qq*4+1] = fmaf(da, x16[qq*4+1], du * bq.y); p = fmaf(x16[qq*4+1], cq.y, p);
      da = exp2f(dlt * aq.z); x16[qq*4+2] = fmaf(da, x16[qq*4+2], du * bq.z); p = fmaf(x16[qq*4+2], cq.z, p);
      da = exp2f(dlt * aq.w); x16[qq*4+3] = fmaf(da, x16[qq*4+3], du * bq.w); p = fmaf(x16[qq*4+3], cq.w, p);
    }
    ypart[(size_t)(b * L + l0 + lo) * D + t] = p;  // overwrites hn tile (staged)
  }
  float4* ex4 = (float4*)(EX + (((size_t)(b * NCH + ch) * D + t) << 4));
  #pragma unroll
  for (int qq = 0; qq < 4; ++qq)
    ex4[qq] = make_float4(x16[qq*4], x16[qq*4+1], x16[qq*4+2], x16[qq*4+3]);
}

// ---------------- K2b: chunk-level scan, in-place E -> X, 4-deep prefetch --
__global__ __launch_bounds__(256) void k2b_chunkscan(
    const float* __restrict__ A, const float* __restrict__ T,
    float* __restrict__ EX) {
  __shared__ float sT[NCH];
  int b = blockIdx.x >> 4;
  int rem = ((blockIdx.x & 15) << 8) | threadIdx.x;  // d*NX + n
  if (threadIdx.x < NCH) sT[threadIdx.x] = T[b * NCH + threadIdx.x];
  __syncthreads();
  float A2 = A[rem] * LOG2E;
  size_t base = ((size_t)b << 18) + rem;  // b*NCH*4096
  float eq[4];
  #pragma unroll
  for (int j = 0; j < 4; ++j) eq[j] = EX[base + ((size_t)j << 12)];
  float x = 0.f;
  #pragma unroll 4
  for (int c = 0; c < NCH; ++c) {
    float e = eq[c & 3];
    if (c + 4 < NCH) eq[c & 3] = EX[base + ((size_t)(c + 4) << 12)];
    EX[base + ((size_t)c << 12)] = x;  // X entering chunk c
    x = fmaf(exp2f(sT[c] * A2), x, e);
  }
}

// ---------------- K2c: wave-per-token fixup + LN2 --------------------------
__global__ __launch_bounds__(256) void k2c_fused(
    const float* __restrict__ y, const float* __restrict__ Win,
    const float* __restrict__ bin_,
    const float* __restrict__ ypart, const float* __restrict__ Cm,
    const float* __restrict__ S, const float* __restrict__ EX,
    const float* __restrict__ A,
    const float* __restrict__ nfg, const float* __restrict__ nfb,
    float* __restrict__ hn2) {
  int t = threadIdx.x;
  int w = t >> 6, lane = t & 63;
  int tok = blockIdx.x * 4 + w;
  int b = tok >> 11;
  int ch = (tok & 2047) >> 5;  // CL = 32
  float vy = y[tok * 32 + (lane & 31)];
  const float4* Win4 = (const float4*)Win;
  float4 acc = ((const float4*)bin_)[lane];
  #pragma unroll
  for (int p = 0; p < 32; ++p) {
    float yp = __shfl(vy, p);
    float4 wv = Win4[p * 64 + lane];
    acc.x = fmaf(yp, wv.x, acc.x);
    acc.y = fmaf(yp, wv.y, acc.y);
    acc.z = fmaf(yp, wv.z, acc.z);
    acc.w = fmaf(yp, wv.w, acc.w);
  }
  // correction: corr[d] = sum_n C[n] * X[d,n] * exp2(A2[d,n]*S)
  float Sl2 = S[tok] * LOG2E;
  float4 c4[4];
  {
    const float4* cr = (const float4*)(Cm + tok * NX);
    #pragma unroll
    for (int qq = 0; qq < 4; ++qq) c4[qq] = cr[qq];
  }
  int d4 = lane * 4;
  const float4* Ar = (const float4*)(A + d4 * NX);
  const float4* Xr = (const float4*)(EX + (((size_t)(b * NCH + ch) * D + d4) << 4));
  float corr[4];
  #pragma unroll
  for (int dj = 0; dj < 4; ++dj) {
    float c = 0.f;
    #pragma unroll
    for (int qq = 0; qq < 4; ++qq) {
      float4 a = Ar[dj * 4 + qq];
      float4 xv = Xr[dj * 4 + qq];
      float4 cc = c4[qq];
      c = fmaf(cc.x * xv.x, exp2f(a.x * Sl2), c);
      c = fmaf(cc.y * xv.y, exp2f(a.y * Sl2), c);
      c = fmaf(cc.z * xv.z, exp2f(a.z * Sl2), c);
      c = fmaf(cc.w * xv.w, exp2f(a.w * Sl2), c);
    }
    corr[dj] = c;
  }
  float4 yp4 = ((const float4*)(ypart + (size_t)tok * D))[lane];
  float4 hf;
  hf.x = acc.x + yp4.x + corr[0];
  hf.y = acc.y + yp4.y + corr[1];
  hf.z = acc.z + yp4.z + corr[2];
  hf.w = acc.w + yp4.w + corr[3];
  float s1 = hf.x + hf.y + hf.z + hf.w;
  float s2 = hf.x * hf.x + hf.y * hf.y + hf.z * hf.z + hf.w * hf.w;
  #pragma unroll
  for (int off = 1; off < 64; off <<= 1) {
    s1 += __shfl_xor(s1, off);
    s2 += __shfl_xor(s2, off);
  }
  float mu = s1 * (1.f / D);
  float var = s2 * (1.f / D) - mu * mu;
  float rstd = rsqrtf(var + 1e-5f);
  float4 g4 = ((const float4*)nfg)[lane];
  float4 b4 = ((const float4*)nfb)[lane];
  float4 o;
  o.x = (hf.x - mu) * rstd * g4.x + b4.x;
  o.y = (hf.y - mu) * rstd * g4.y + b4.y;
  o.z = (hf.z - mu) * rstd * g4.z + b4.z;
  o.w = (hf.w - mu) * rstd * g4.w + b4.w;
  ((float4*)(hn2 + (size_t)tok * D))[lane] = o;
}

__device__ __forceinline__ float gelu_exact(float x) {
  return 0.5f * x * (1.f + erff(x * 0.70710678118654752440f));
}

// ---------------- K3b: MLP (unchanged this round) ---------------------------
__global__ __launch_bounds__(256) void k3b_mlp(
    const float* __restrict__ hn2, const float* __restrict__ W1,
    const float* __restrict__ b1, const float* __restrict__ W2,
    const float* __restrict__ b2, float* __restrict__ out) {
  __shared__ float s_az[32 * 260];
  __shared__ float s_w[32 * 256];
  int t = threadIdx.x;
  int tok0 = blockIdx.x * 32;
  {
    const float4* src = (const float4*)(hn2 + (size_t)tok0 * D);
    float4* dst = (float4*)s_az;
    for (int i = t; i < 2048; i += 256) dst[i] = src[i];
  }
  float4 acc[8];
  #pragma unroll
  for (int jj = 0; jj < 8; ++jj) acc[jj] = make_float4(0.f, 0.f, 0.f, 0.f);
  int dcol = t & 63, jrow = t >> 6;
  int d4 = dcol * 4, j8 = jrow * 8;
  for (int kb = 0; kb < 256; kb += 32) {
    __syncthreads();
    {
      const float4* wsrc = (const float4*)(W1 + kb * D);
      float4* wdst = (float4*)s_w;
      for (int i = t; i < 2048; i += 256) wdst[i] = wsrc[i];
    }
    __syncthreads();
    #pragma unroll 8
    for (int k = 0; k < 32; ++k) {
      float4 w = *(float4*)&s_w[k * D + d4];
      #pragma unroll
      for (int jj = 0; jj < 8; ++jj) {
        float av = s_az[(j8 + jj) * 256 + kb + k];
        acc[jj].x = fmaf(av, w.x, acc[jj].x);
        acc[jj].y = fmaf(av, w.y, acc[jj].y);
        acc[jj].z = fmaf(av, w.z, acc[jj].z);
        acc[jj].w = fmaf(av, w.w, acc[jj].w);
      }
    }
  }
  float4 b1v = *(const float4*)&b1[d4];
  __syncthreads();
  #pragma unroll
  for (int jj = 0; jj < 8; ++jj) {
    float4 v = acc[jj];
    v.x = gelu_exact(v.x + b1v.x);
    v.y = gelu_exact(v.y + b1v.y);
    v.z = gelu_exact(v.z + b1v.z);
    v.w = gelu_exact(v.w + b1v.w);
    *(float4*)&s_az[(j8 + jj) * 260 + d4] = v;
  }
  {
    const float4* w2s = (const float4*)W2;
    float4* wdst = (float4*)s_w;
    for (int i = t; i < 2048; i += 256) wdst[i] = w2s[i];
  }
  __syncthreads();
  int j = t >> 3, p4 = (t & 7) * 4;
  float4 o = make_float4(0.f, 0.f, 0.f, 0.f);
  for (int dd = 0; dd < 256; ++dd) {
    float zv = s_az[j * 260 + dd];
    float4 w = *(float4*)&s_w[dd * 32 + p4];
    o.x = fmaf(zv, w.x, o.x);
    o.y = fmaf(zv, w.y, o.y);
    o.z = fmaf(zv, w.z, o.z);
    o.w = fmaf(zv, w.w, o.w);
  }
  float4 b2v = *(const float4*)&b2[p4];
  o.x += b2v.x; o.y += b2v.y; o.z += b2v.z; o.w += b2v.w;
  *(float4*)&out[(size_t)(tok0 + j) * 32 + p4] = o;
}

extern "C" void kernel_launch(void* const* d_in, const int* in_sizes, int n_in,
                              void* d_out, int out_size, void* d_ws, size_t ws_size,
                              hipStream_t stream) {
  const float* y    = (const float*)d_in[0];
  const float* Win  = (const float*)d_in[1];
  const float* bin_ = (const float*)d_in[2];
  const float* ng   = (const float*)d_in[3];
  const float* nb   = (const float*)d_in[4];
  const float* A    = (const float*)d_in[5];
  const float* WB   = (const float*)d_in[6];
  const float* WC   = (const float*)d_in[7];
  const float* qd   = (const float*)d_in[8];
  const float* pd   = (const float*)d_in[9];
  const float* nfg  = (const float*)d_in[10];
  const float* nfb  = (const float*)d_in[11];
  const float* W1   = (const float*)d_in[12];
  const float* b1   = (const float*)d_in[13];
  const float* W2   = (const float*)d_in[14];
  const float* b2   = (const float*)d_in[15];

  float* ws = (float*)d_ws;
  float* hnbuf = ws;                          // NTOK*D; hn -> ypart -> hn2
  float* delta = ws + 4194304;                // NTOK
  float* Bm    = delta + NTOK;                // NTOK*NX
  float* Cm    = Bm + NTOK * NX;              // NTOK*NX
  float* Sbuf  = Cm + NTOK * NX;              // NTOK
  float* Tbuf  = Sbuf + NTOK;                 // NBATCH*NCH = 512
  float* EX    = Tbuf + NBATCH * NCH;         // NBATCH*NCH*D*NX = 2M floats

  k1_front<<<NTOK / 4, 256, 0, stream>>>(y, Win, bin_, ng, nb, WB, WC, qd, pd,
                                         hnbuf, delta, Bm, Cm);
  k2a_local<<<NBATCH * NCH, 256, 0, stream>>>(hnbuf, delta, Bm, Cm, A,
                                              hnbuf, EX, Sbuf, Tbuf);
  k2b_chunkscan<<<NBATCH * 16, 256, 0, stream>>>(A, Tbuf, EX);
  k2c_fused<<<NTOK / 4, 256, 0, stream>>>(y, Win, bin_, hnbuf, Cm, Sbuf, EX, A,
                                          nfg, nfb, hnbuf);
  k3b_mlp<<<NTOK / 32, 256, 0, stream>>>(hnbuf, W1, b1, W2, b2, (float*)d_out);
}

// Round 4
// 287.394 us; speedup vs baseline: 1.1894x; 1.1894x over previous
//
#include <hip/hip_runtime.h>
#include <math.h>

#define D 256
#define NX 16
#define L 2048
#define NBATCH 8
#define NTOK (NBATCH * L)
#define CL 32
#define NCH (L / CL)  // 64
#define LOG2E 1.44269504088896340736f

// ---------------- K0: A -> At[n][d] with LOG2E folded ----------------
__global__ __launch_bounds__(256) void k0_at(const float* __restrict__ A,
                                             float* __restrict__ At) {
  int i = blockIdx.x * 256 + threadIdx.x;  // 4096 total
  int d = i >> 4, n = i & 15;
  At[n * D + d] = A[i] * LOG2E;
}

// ---------------- K1: wave-per-token front end ----------------
// h = y@Win + bin (regs); hn = LN(h); delta; Bm; Cm; also stores (mu, irs).
__global__ __launch_bounds__(256) void k1_front(
    const float* __restrict__ y, const float* __restrict__ Win,
    const float* __restrict__ bin_, const float* __restrict__ ng,
    const float* __restrict__ nb, const float* __restrict__ WB,
    const float* __restrict__ WC, const float* __restrict__ qd,
    const float* __restrict__ pd,
    float* __restrict__ hn, float* __restrict__ delta,
    float* __restrict__ Bm, float* __restrict__ Cm,
    float* __restrict__ muv, float* __restrict__ irsv) {
  __shared__ float s_hn[4][D];
  int t = threadIdx.x;
  int w = t >> 6, lane = t & 63;
  int tok = blockIdx.x * 4 + w;
  float vy = y[tok * 32 + (lane & 31)];
  const float4* Win4 = (const float4*)Win;  // [p][64 float4]
  float4 acc = ((const float4*)bin_)[lane];
  #pragma unroll
  for (int p = 0; p < 32; ++p) {
    float yp = __shfl(vy, p);
    float4 wv = Win4[p * 64 + lane];
    acc.x = fmaf(yp, wv.x, acc.x);
    acc.y = fmaf(yp, wv.y, acc.y);
    acc.z = fmaf(yp, wv.z, acc.z);
    acc.w = fmaf(yp, wv.w, acc.w);
  }
  float s1 = acc.x + acc.y + acc.z + acc.w;
  float s2 = acc.x * acc.x + acc.y * acc.y + acc.z * acc.z + acc.w * acc.w;
  #pragma unroll
  for (int off = 1; off < 64; off <<= 1) {
    s1 += __shfl_xor(s1, off);
    s2 += __shfl_xor(s2, off);
  }
  float mu = s1 * (1.f / D);
  float var = s2 * (1.f / D) - mu * mu;
  float rstd = rsqrtf(var + 1e-5f);
  if (lane == 0) { muv[tok] = mu; irsv[tok] = sqrtf(var + 1e-5f); }
  float4 g4 = ((const float4*)ng)[lane];
  float4 b4 = ((const float4*)nb)[lane];
  float4 v4;
  v4.x = (acc.x - mu) * rstd * g4.x + b4.x;
  v4.y = (acc.y - mu) * rstd * g4.y + b4.y;
  v4.z = (acc.z - mu) * rstd * g4.z + b4.z;
  v4.w = (acc.w - mu) * rstd * g4.w + b4.w;
  ((float4*)(hn + (size_t)tok * D))[lane] = v4;
  *(float4*)&s_hn[w][lane * 4] = v4;
  float4 q4 = ((const float4*)qd)[lane];
  float dd = v4.x * q4.x + v4.y * q4.y + v4.z * q4.z + v4.w * q4.w;
  #pragma unroll
  for (int off = 1; off < 64; off <<= 1) dd += __shfl_xor(dd, off);
  if (lane == 0) {
    float xx = pd[0] + dd;
    delta[tok] = (xx > 20.f) ? xx : log1pf(expf(xx));
  }
  int n = lane & 15, q = lane >> 4;
  const float4* wbr = (const float4*)(WB + n * D + q * 64);
  const float4* wcr = (const float4*)(WC + n * D + q * 64);
  const float4* hq = (const float4*)&s_hn[w][q * 64];
  float pB = 0.f, pC = 0.f;
  #pragma unroll
  for (int j = 0; j < 16; ++j) {
    float4 hv = hq[j];
    float4 wb = wbr[j];
    float4 wc = wcr[j];
    pB += hv.x * wb.x + hv.y * wb.y + hv.z * wb.z + hv.w * wb.w;
    pC += hv.x * wc.x + hv.y * wc.y + hv.z * wc.z + hv.w * wc.w;
  }
  pB += __shfl_xor(pB, 16); pB += __shfl_xor(pB, 32);
  pC += __shfl_xor(pC, 16); pC += __shfl_xor(pC, 32);
  if (lane < 16) Bm[tok * NX + lane] = pB;
  else if (lane < 32) Cm[tok * NX + (lane - 16)] = pC;
}

// ---------------- K2a: local chunk scans -> end states E only --------------
// Block = (b, chunk); thread = d; x[16] in regs. EX layout [bc][n][d].
__global__ __launch_bounds__(256) void k2a_local(
    const float* __restrict__ hn, const float* __restrict__ delta,
    const float* __restrict__ Bm, const float* __restrict__ At,
    float* __restrict__ EX, float* __restrict__ T) {
  __shared__ float shn[CL][D];  // 32 KB
  __shared__ float sB[CL][NX];
  __shared__ float sdelta[CL];
  int ch = blockIdx.x & (NCH - 1);
  int b = blockIdx.x >> 6;
  int t = threadIdx.x;  // = d
  size_t tokbase = (size_t)(b * L + ch * CL);
  if (t < CL) sdelta[t] = delta[tokbase + t];
  for (int i = t; i < CL * NX; i += 256) ((float*)sB)[i] = Bm[tokbase * NX + i];
  {
    const float4* src = (const float4*)(hn + tokbase * D);
    float4* dst = (float4*)shn;
    #pragma unroll
    for (int i = 0; i < 8; ++i) dst[t + 256 * i] = src[t + 256 * i];
  }
  float a16[16];
  #pragma unroll
  for (int n = 0; n < 16; ++n) a16[n] = At[n * D + t];
  __syncthreads();
  if (t < 32) {  // chunk delta total
    float v = sdelta[t];
    #pragma unroll
    for (int off = 1; off < 32; off <<= 1) v += __shfl_xor(v, off);
    if (t == 0) T[b * NCH + ch] = v;
  }
  float x16[16];
  #pragma unroll
  for (int n = 0; n < 16; ++n) x16[n] = 0.f;
  for (int lo = 0; lo < CL; ++lo) {
    float dlt = sdelta[lo];
    float du = dlt * shn[lo][t];
    #pragma unroll
    for (int n = 0; n < 16; ++n)
      x16[n] = fmaf(exp2f(dlt * a16[n]), x16[n], du * sB[lo][n]);
  }
  size_t exbase = (size_t)blockIdx.x * (NX * D) + t;
  #pragma unroll
  for (int n = 0; n < 16; ++n) EX[exbase + n * D] = x16[n];
}

// ---------------- K2b: chunk-level scan, in-place E -> X, prefetch ---------
__global__ __launch_bounds__(256) void k2b_chunkscan(
    const float* __restrict__ At, const float* __restrict__ T,
    float* __restrict__ EX) {
  __shared__ float sT[NCH];
  int b = blockIdx.x >> 4;
  int rem = ((blockIdx.x & 15) << 8) | threadIdx.x;  // n*D + d
  if (threadIdx.x < NCH) sT[threadIdx.x] = T[b * NCH + threadIdx.x];
  __syncthreads();
  float A2 = At[rem];  // already *LOG2E
  size_t base = ((size_t)b << 18) + rem;  // b*NCH*4096
  float eq[4];
  #pragma unroll
  for (int j = 0; j < 4; ++j) eq[j] = EX[base + ((size_t)j << 12)];
  float x = 0.f;
  #pragma unroll 4
  for (int c = 0; c < NCH; ++c) {
    float e = eq[c & 3];
    if (c + 4 < NCH) eq[c & 3] = EX[base + ((size_t)(c + 4) << 12)];
    EX[base + ((size_t)c << 12)] = x;  // X entering chunk c
    x = fmaf(exp2f(sT[c] * A2), x, e);
  }
}

// ---------------- K2c: re-scan with true init state + h recon + LN2 --------
// Block = (b, chunk); thread = d. Writes hn2 in-place over hn (own tile only).
__global__ __launch_bounds__(256) void k2c_scan2(
    const float* __restrict__ hn, const float* __restrict__ delta,
    const float* __restrict__ Bm, const float* __restrict__ Cm,
    const float* __restrict__ At, const float* __restrict__ EX,
    const float* __restrict__ muv, const float* __restrict__ irsv,
    const float* __restrict__ ng, const float* __restrict__ nb,
    const float* __restrict__ nfg, const float* __restrict__ nfb,
    float* __restrict__ hn2) {
  __shared__ float shn[CL][D];  // hn tile, then final-y tile
  __shared__ float sB[CL][NX];
  __shared__ float sC[CL][NX];
  __shared__ float sdelta[CL];
  __shared__ float smu[CL];
  __shared__ float sirs[CL];
  int ch = blockIdx.x & (NCH - 1);
  int b = blockIdx.x >> 6;
  int t = threadIdx.x;  // = d
  size_t tokbase = (size_t)(b * L + ch * CL);
  if (t < CL) {
    sdelta[t] = delta[tokbase + t];
    smu[t] = muv[tokbase + t];
    sirs[t] = irsv[tokbase + t];
  }
  for (int i = t; i < CL * NX; i += 256) {
    ((float*)sB)[i] = Bm[tokbase * NX + i];
    ((float*)sC)[i] = Cm[tokbase * NX + i];
  }
  {
    const float4* src = (const float4*)(hn + tokbase * D);
    float4* dst = (float4*)shn;
    #pragma unroll
    for (int i = 0; i < 8; ++i) dst[t + 256 * i] = src[t + 256 * i];
  }
  float a16[16], x16[16];
  size_t exbase = (size_t)blockIdx.x * (NX * D) + t;
  #pragma unroll
  for (int n = 0; n < 16; ++n) {
    a16[n] = At[n * D + t];
    x16[n] = EX[exbase + n * D];
  }
  float nb_d = nb[t];
  float invg = 1.0f / ng[t];
  __syncthreads();
  for (int lo = 0; lo < CL; ++lo) {
    float dlt = sdelta[lo];
    float hv = shn[lo][t];
    float du = dlt * hv;
    float p = 0.f;
    #pragma unroll
    for (int n = 0; n < 16; ++n) {
      x16[n] = fmaf(exp2f(dlt * a16[n]), x16[n], du * sB[lo][n]);
      p = fmaf(x16[n], sC[lo][n], p);
    }
    // reconstruct h = (hn - nb)/ng * sqrt(var+eps) + mu, add scan output
    float h = fmaf((hv - nb_d) * invg, sirs[lo], smu[lo]);
    shn[lo][t] = h + p;  // own (lo,t) slot only -> no sync needed
  }
  __syncthreads();
  // LN2: wave w handles tokens w*8 .. w*8+7
  int w = t >> 6, lane = t & 63;
  float4 g4 = ((const float4*)nfg)[lane];
  float4 b4 = ((const float4*)nfb)[lane];
  for (int j = 0; j < 8; ++j) {
    int lo = w * 8 + j;
    float4 v = *(float4*)&shn[lo][lane * 4];
    float s1 = v.x + v.y + v.z + v.w;
    float s2 = v.x * v.x + v.y * v.y + v.z * v.z + v.w * v.w;
    #pragma unroll
    for (int off = 1; off < 64; off <<= 1) {
      s1 += __shfl_xor(s1, off);
      s2 += __shfl_xor(s2, off);
    }
    float mu2 = s1 * (1.f / D);
    float var2 = s2 * (1.f / D) - mu2 * mu2;
    float rstd2 = rsqrtf(var2 + 1e-5f);
    float4 o;
    o.x = (v.x - mu2) * rstd2 * g4.x + b4.x;
    o.y = (v.y - mu2) * rstd2 * g4.y + b4.y;
    o.z = (v.z - mu2) * rstd2 * g4.z + b4.z;
    o.w = (v.w - mu2) * rstd2 * g4.w + b4.w;
    ((float4*)(hn2 + (tokbase + lo) * D))[lane] = o;
  }
}

__device__ __forceinline__ float gelu_exact(float x) {
  return 0.5f * x * (1.f + erff(x * 0.70710678118654752440f));
}

// ---------------- K3b: MLP (unchanged) --------------------------------------
__global__ __launch_bounds__(256) void k3b_mlp(
    const float* __restrict__ hn2, const float* __restrict__ W1,
    const float* __restrict__ b1, const float* __restrict__ W2,
    const float* __restrict__ b2, float* __restrict__ out) {
  __shared__ float s_az[32 * 260];
  __shared__ float s_w[32 * 256];
  int t = threadIdx.x;
  int tok0 = blockIdx.x * 32;
  {
    const float4* src = (const float4*)(hn2 + (size_t)tok0 * D);
    float4* dst = (float4*)s_az;
    for (int i = t; i < 2048; i += 256) dst[i] = src[i];
  }
  float4 acc[8];
  #pragma unroll
  for (int jj = 0; jj < 8; ++jj) acc[jj] = make_float4(0.f, 0.f, 0.f, 0.f);
  int dcol = t & 63, jrow = t >> 6;
  int d4 = dcol * 4, j8 = jrow * 8;
  for (int kb = 0; kb < 256; kb += 32) {
    __syncthreads();
    {
      const float4* wsrc = (const float4*)(W1 + kb * D);
      float4* wdst = (float4*)s_w;
      for (int i = t; i < 2048; i += 256) wdst[i] = wsrc[i];
    }
    __syncthreads();
    #pragma unroll 8
    for (int k = 0; k < 32; ++k) {
      float4 w = *(float4*)&s_w[k * D + d4];
      #pragma unroll
      for (int jj = 0; jj < 8; ++jj) {
        float av = s_az[(j8 + jj) * 256 + kb + k];
        acc[jj].x = fmaf(av, w.x, acc[jj].x);
        acc[jj].y = fmaf(av, w.y, acc[jj].y);
        acc[jj].z = fmaf(av, w.z, acc[jj].z);
        acc[jj].w = fmaf(av, w.w, acc[jj].w);
      }
    }
  }
  float4 b1v = *(const float4*)&b1[d4];
  __syncthreads();
  #pragma unroll
  for (int jj = 0; jj < 8; ++jj) {
    float4 v = acc[jj];
    v.x = gelu_exact(v.x + b1v.x);
    v.y = gelu_exact(v.y + b1v.y);
    v.z = gelu_exact(v.z + b1v.z);
    v.w = gelu_exact(v.w + b1v.w);
    *(float4*)&s_az[(j8 + jj) * 260 + d4] = v;
  }
  {
    const float4* w2s = (const float4*)W2;
    float4* wdst = (float4*)s_w;
    for (int i = t; i < 2048; i += 256) wdst[i] = w2s[i];
  }
  __syncthreads();
  int j = t >> 3, p4 = (t & 7) * 4;
  float4 o = make_float4(0.f, 0.f, 0.f, 0.f);
  for (int dd = 0; dd < 256; ++dd) {
    float zv = s_az[j * 260 + dd];
    float4 w = *(float4*)&s_w[dd * 32 + p4];
    o.x = fmaf(zv, w.x, o.x);
    o.y = fmaf(zv, w.y, o.y);
    o.z = fmaf(zv, w.z, o.z);
    o.w = fmaf(zv, w.w, o.w);
  }
  float4 b2v = *(const float4*)&b2[p4];
  o.x += b2v.x; o.y += b2v.y; o.z += b2v.z; o.w += b2v.w;
  *(float4*)&out[(size_t)(tok0 + j) * 32 + p4] = o;
}

extern "C" void kernel_launch(void* const* d_in, const int* in_sizes, int n_in,
                              void* d_out, int out_size, void* d_ws, size_t ws_size,
                              hipStream_t stream) {
  const float* y    = (const float*)d_in[0];
  const float* Win  = (const float*)d_in[1];
  const float* bin_ = (const float*)d_in[2];
  const float* ng   = (const float*)d_in[3];
  const float* nb   = (const float*)d_in[4];
  const float* A    = (const float*)d_in[5];
  const float* WB   = (const float*)d_in[6];
  const float* WC   = (const float*)d_in[7];
  const float* qd   = (const float*)d_in[8];
  const float* pd   = (const float*)d_in[9];
  const float* nfg  = (const float*)d_in[10];
  const float* nfb  = (const float*)d_in[11];
  const float* W1   = (const float*)d_in[12];
  const float* b1   = (const float*)d_in[13];
  const float* W2   = (const float*)d_in[14];
  const float* b2   = (const float*)d_in[15];

  float* ws = (float*)d_ws;
  float* hnbuf = ws;                          // NTOK*D; hn -> (in-place) hn2
  float* delta = ws + 4194304;                // NTOK
  float* Bm    = delta + NTOK;                // NTOK*NX
  float* Cm    = Bm + NTOK * NX;              // NTOK*NX
  float* muv   = Cm + NTOK * NX;              // NTOK
  float* irsv  = muv + NTOK;                  // NTOK
  float* Tbuf  = irsv + NTOK;                 // NBATCH*NCH = 512
  float* At    = Tbuf + NBATCH * NCH;         // 4096
  float* EX    = At + D * NX;                 // NBATCH*NCH*D*NX = 2M floats

  k0_at<<<16, 256, 0, stream>>>(A, At);
  k1_front<<<NTOK / 4, 256, 0, stream>>>(y, Win, bin_, ng, nb, WB, WC, qd, pd,
                                         hnbuf, delta, Bm, Cm, muv, irsv);
  k2a_local<<<NBATCH * NCH, 256, 0, stream>>>(hnbuf, delta, Bm, At, EX, Tbuf);
  k2b_chunkscan<<<NBATCH * 16, 256, 0, stream>>>(At, Tbuf, EX);
  k2c_scan2<<<NBATCH * NCH, 256, 0, stream>>>(hnbuf, delta, Bm, Cm, At, EX,
                                              muv, irsv, ng, nb, nfg, nfb,
                                              hnbuf);
  k3b_mlp<<<NTOK / 32, 256, 0, stream>>>(hnbuf, W1, b1, W2, b2, (float*)d_out);
}

// Round 5
// 285.271 us; speedup vs baseline: 1.1982x; 1.0074x over previous
//
#include <hip/hip_runtime.h>
#include <math.h>

#define D 256
#define NX 16
#define L 2048
#define NBATCH 8
#define NTOK (NBATCH * L)
#define CL 32
#define NCH (L / CL)  // 64
#define LOG2E 1.44269504088896340736f

// ---------------- K0: A -> At[n][d] with LOG2E folded ----------------
__global__ __launch_bounds__(256) void k0_at(const float* __restrict__ A,
                                             float* __restrict__ At) {
  int i = blockIdx.x * 256 + threadIdx.x;  // 4096 total
  int d = i >> 4, n = i & 15;
  At[n * D + d] = A[i] * LOG2E;
}

// ---------------- K1: wave-per-token front end (no-shfl matmul) -------------
// h = y@Win + bin (regs); hn = LN(h); delta; Bm; Cm; stores (mu, sqrt(var+eps)).
__global__ __launch_bounds__(256) void k1_front(
    const float* __restrict__ y, const float* __restrict__ Win,
    const float* __restrict__ bin_, const float* __restrict__ ng,
    const float* __restrict__ nb, const float* __restrict__ WB,
    const float* __restrict__ WC, const float* __restrict__ qd,
    const float* __restrict__ pd,
    float* __restrict__ hn, float* __restrict__ delta,
    float* __restrict__ Bm, float* __restrict__ Cm,
    float* __restrict__ muv, float* __restrict__ irsv) {
  __shared__ float s_hn[4][D];  // XOR-swizzled: block q rotated by q*8 floats
  int t = threadIdx.x;
  int w = __builtin_amdgcn_readfirstlane(t >> 6);  // wave id, provably uniform
  int lane = t & 63;
  int tok = blockIdx.x * 4 + w;                    // uniform per wave
  // y row through a uniform pointer -> scalar loads, no cross-lane ops needed
  const float* yrow = y + tok * 32;
  float ys[32];
  #pragma unroll
  for (int p = 0; p < 32; ++p) ys[p] = yrow[p];
  const float4* Win4 = (const float4*)Win;  // [p][64 float4]
  float4 acc = ((const float4*)bin_)[lane];
  #pragma unroll
  for (int p = 0; p < 32; ++p) {
    float4 wv = Win4[p * 64 + lane];
    acc.x = fmaf(ys[p], wv.x, acc.x);
    acc.y = fmaf(ys[p], wv.y, acc.y);
    acc.z = fmaf(ys[p], wv.z, acc.z);
    acc.w = fmaf(ys[p], wv.w, acc.w);
  }
  float s1 = acc.x + acc.y + acc.z + acc.w;
  float s2 = acc.x * acc.x + acc.y * acc.y + acc.z * acc.z + acc.w * acc.w;
  #pragma unroll
  for (int off = 1; off < 64; off <<= 1) {
    s1 += __shfl_xor(s1, off);
    s2 += __shfl_xor(s2, off);
  }
  float mu = s1 * (1.f / D);
  float var = s2 * (1.f / D) - mu * mu;
  float rstd = rsqrtf(var + 1e-5f);
  if (lane == 0) { muv[tok] = mu; irsv[tok] = sqrtf(var + 1e-5f); }
  float4 g4 = ((const float4*)ng)[lane];
  float4 b4 = ((const float4*)nb)[lane];
  float4 v4;
  v4.x = (acc.x - mu) * rstd * g4.x + b4.x;
  v4.y = (acc.y - mu) * rstd * g4.y + b4.y;
  v4.z = (acc.z - mu) * rstd * g4.z + b4.z;
  v4.w = (acc.w - mu) * rstd * g4.w + b4.w;
  ((float4*)(hn + (size_t)tok * D))[lane] = v4;
  // swizzled LDS store: lane owns d = lane*4..+3; q-block = lane>>4
  {
    int qw = lane >> 4, jo = (lane & 15) * 4;
    *(float4*)&s_hn[w][qw * 64 + ((jo + qw * 8) & 63)] = v4;
  }
  float4 q4 = ((const float4*)qd)[lane];
  float dd = v4.x * q4.x + v4.y * q4.y + v4.z * q4.z + v4.w * q4.w;
  #pragma unroll
  for (int off = 1; off < 64; off <<= 1) dd += __shfl_xor(dd, off);
  if (lane == 0) {
    float xx = pd[0] + dd;
    delta[tok] = (xx > 20.f) ? xx : log1pf(expf(xx));
  }
  // B/C projections: lane = (q = lane>>4, n = lane&15); q covers d in [q*64,+64)
  int n = lane & 15, q = lane >> 4;
  const float4* wbr = (const float4*)(WB + n * D + q * 64);
  const float4* wcr = (const float4*)(WC + n * D + q * 64);
  float pB = 0.f, pC = 0.f;
  #pragma unroll
  for (int j = 0; j < 16; ++j) {
    float4 hv = *(float4*)&s_hn[w][q * 64 + ((j * 4 + q * 8) & 63)];  // conflict-free
    float4 wb = wbr[j];
    float4 wc = wcr[j];
    pB += hv.x * wb.x + hv.y * wb.y + hv.z * wb.z + hv.w * wb.w;
    pC += hv.x * wc.x + hv.y * wc.y + hv.z * wc.z + hv.w * wc.w;
  }
  pB += __shfl_xor(pB, 16); pB += __shfl_xor(pB, 32);
  pC += __shfl_xor(pC, 16); pC += __shfl_xor(pC, 32);
  if (lane < 16) Bm[tok * NX + lane] = pB;
  else if (lane < 32) Cm[tok * NX + (lane - 16)] = pC;
}

// ---------------- K2a: local chunk scans -> end states E only --------------
__global__ __launch_bounds__(256) void k2a_local(
    const float* __restrict__ hn, const float* __restrict__ delta,
    const float* __restrict__ Bm, const float* __restrict__ At,
    float* __restrict__ EX, float* __restrict__ T) {
  __shared__ float shn[CL][D];  // 32 KB
  __shared__ float sB[CL][NX];
  __shared__ float sdelta[CL];
  int ch = blockIdx.x & (NCH - 1);
  int b = blockIdx.x >> 6;
  int t = threadIdx.x;  // = d
  size_t tokbase = (size_t)(b * L + ch * CL);
  if (t < CL) sdelta[t] = delta[tokbase + t];
  for (int i = t; i < CL * NX; i += 256) ((float*)sB)[i] = Bm[tokbase * NX + i];
  {
    const float4* src = (const float4*)(hn + tokbase * D);
    float4* dst = (float4*)shn;
    #pragma unroll
    for (int i = 0; i < 8; ++i) dst[t + 256 * i] = src[t + 256 * i];
  }
  float a16[16];
  #pragma unroll
  for (int n = 0; n < 16; ++n) a16[n] = At[n * D + t];
  __syncthreads();
  if (t < 32) {
    float v = sdelta[t];
    #pragma unroll
    for (int off = 1; off < 32; off <<= 1) v += __shfl_xor(v, off);
    if (t == 0) T[b * NCH + ch] = v;
  }
  float x16[16];
  #pragma unroll
  for (int n = 0; n < 16; ++n) x16[n] = 0.f;
  for (int lo = 0; lo < CL; ++lo) {
    float dlt = sdelta[lo];
    float du = dlt * shn[lo][t];
    #pragma unroll
    for (int n = 0; n < 16; ++n)
      x16[n] = fmaf(exp2f(dlt * a16[n]), x16[n], du * sB[lo][n]);
  }
  size_t exbase = (size_t)blockIdx.x * (NX * D) + t;
  #pragma unroll
  for (int n = 0; n < 16; ++n) EX[exbase + n * D] = x16[n];
}

// ---------------- K2b: chunk-level scan, in-place E -> X, prefetch ---------
__global__ __launch_bounds__(256) void k2b_chunkscan(
    const float* __restrict__ At, const float* __restrict__ T,
    float* __restrict__ EX) {
  __shared__ float sT[NCH];
  int b = blockIdx.x >> 4;
  int rem = ((blockIdx.x & 15) << 8) | threadIdx.x;  // n*D + d
  if (threadIdx.x < NCH) sT[threadIdx.x] = T[b * NCH + threadIdx.x];
  __syncthreads();
  float A2 = At[rem];  // already *LOG2E
  size_t base = ((size_t)b << 18) + rem;
  float eq[4];
  #pragma unroll
  for (int j = 0; j < 4; ++j) eq[j] = EX[base + ((size_t)j << 12)];
  float x = 0.f;
  #pragma unroll 4
  for (int c = 0; c < NCH; ++c) {
    float e = eq[c & 3];
    if (c + 4 < NCH) eq[c & 3] = EX[base + ((size_t)(c + 4) << 12)];
    EX[base + ((size_t)c << 12)] = x;
    x = fmaf(exp2f(sT[c] * A2), x, e);
  }
}

// ---------------- K2c: re-scan with true init state + h recon + LN2 --------
__global__ __launch_bounds__(256) void k2c_scan2(
    const float* __restrict__ hn, const float* __restrict__ delta,
    const float* __restrict__ Bm, const float* __restrict__ Cm,
    const float* __restrict__ At, const float* __restrict__ EX,
    const float* __restrict__ muv, const float* __restrict__ irsv,
    const float* __restrict__ ng, const float* __restrict__ nb,
    const float* __restrict__ nfg, const float* __restrict__ nfb,
    float* __restrict__ hn2) {
  __shared__ float shn[CL][D];
  __shared__ float sB[CL][NX];
  __shared__ float sC[CL][NX];
  __shared__ float sdelta[CL];
  __shared__ float smu[CL];
  __shared__ float sirs[CL];
  int ch = blockIdx.x & (NCH - 1);
  int b = blockIdx.x >> 6;
  int t = threadIdx.x;  // = d
  size_t tokbase = (size_t)(b * L + ch * CL);
  if (t < CL) {
    sdelta[t] = delta[tokbase + t];
    smu[t] = muv[tokbase + t];
    sirs[t] = irsv[tokbase + t];
  }
  for (int i = t; i < CL * NX; i += 256) {
    ((float*)sB)[i] = Bm[tokbase * NX + i];
    ((float*)sC)[i] = Cm[tokbase * NX + i];
  }
  {
    const float4* src = (const float4*)(hn + tokbase * D);
    float4* dst = (float4*)shn;
    #pragma unroll
    for (int i = 0; i < 8; ++i) dst[t + 256 * i] = src[t + 256 * i];
  }
  float a16[16], x16[16];
  size_t exbase = (size_t)blockIdx.x * (NX * D) + t;
  #pragma unroll
  for (int n = 0; n < 16; ++n) {
    a16[n] = At[n * D + t];
    x16[n] = EX[exbase + n * D];
  }
  float nb_d = nb[t];
  float invg = 1.0f / ng[t];
  __syncthreads();
  for (int lo = 0; lo < CL; ++lo) {
    float dlt = sdelta[lo];
    float hv = shn[lo][t];
    float du = dlt * hv;
    float p = 0.f;
    #pragma unroll
    for (int n = 0; n < 16; ++n) {
      x16[n] = fmaf(exp2f(dlt * a16[n]), x16[n], du * sB[lo][n]);
      p = fmaf(x16[n], sC[lo][n], p);
    }
    float h = fmaf((hv - nb_d) * invg, sirs[lo], smu[lo]);
    shn[lo][t] = h + p;
  }
  __syncthreads();
  int w = t >> 6, lane = t & 63;
  float4 g4 = ((const float4*)nfg)[lane];
  float4 b4 = ((const float4*)nfb)[lane];
  for (int j = 0; j < 8; ++j) {
    int lo = w * 8 + j;
    float4 v = *(float4*)&shn[lo][lane * 4];
    float s1 = v.x + v.y + v.z + v.w;
    float s2 = v.x * v.x + v.y * v.y + v.z * v.z + v.w * v.w;
    #pragma unroll
    for (int off = 1; off < 64; off <<= 1) {
      s1 += __shfl_xor(s1, off);
      s2 += __shfl_xor(s2, off);
    }
    float mu2 = s1 * (1.f / D);
    float var2 = s2 * (1.f / D) - mu2 * mu2;
    float rstd2 = rsqrtf(var2 + 1e-5f);
    float4 o;
    o.x = (v.x - mu2) * rstd2 * g4.x + b4.x;
    o.y = (v.y - mu2) * rstd2 * g4.y + b4.y;
    o.z = (v.z - mu2) * rstd2 * g4.z + b4.z;
    o.w = (v.w - mu2) * rstd2 * g4.w + b4.w;
    ((float4*)(hn2 + (tokbase + lo) * D))[lane] = o;
  }
}

__device__ __forceinline__ float gelu_exact(float x) {
  return 0.5f * x * (1.f + erff(x * 0.70710678118654752440f));
}

// ---------------- K3b: MLP (unchanged) --------------------------------------
__global__ __launch_bounds__(256) void k3b_mlp(
    const float* __restrict__ hn2, const float* __restrict__ W1,
    const float* __restrict__ b1, const float* __restrict__ W2,
    const float* __restrict__ b2, float* __restrict__ out) {
  __shared__ float s_az[32 * 260];
  __shared__ float s_w[32 * 256];
  int t = threadIdx.x;
  int tok0 = blockIdx.x * 32;
  {
    const float4* src = (const float4*)(hn2 + (size_t)tok0 * D);
    float4* dst = (float4*)s_az;
    for (int i = t; i < 2048; i += 256) dst[i] = src[i];
  }
  float4 acc[8];
  #pragma unroll
  for (int jj = 0; jj < 8; ++jj) acc[jj] = make_float4(0.f, 0.f, 0.f, 0.f);
  int dcol = t & 63, jrow = t >> 6;
  int d4 = dcol * 4, j8 = jrow * 8;
  for (int kb = 0; kb < 256; kb += 32) {
    __syncthreads();
    {
      const float4* wsrc = (const float4*)(W1 + kb * D);
      float4* wdst = (float4*)s_w;
      for (int i = t; i < 2048; i += 256) wdst[i] = wsrc[i];
    }
    __syncthreads();
    #pragma unroll 8
    for (int k = 0; k < 32; ++k) {
      float4 w = *(float4*)&s_w[k * D + d4];
      #pragma unroll
      for (int jj = 0; jj < 8; ++jj) {
        float av = s_az[(j8 + jj) * 256 + kb + k];
        acc[jj].x = fmaf(av, w.x, acc[jj].x);
        acc[jj].y = fmaf(av, w.y, acc[jj].y);
        acc[jj].z = fmaf(av, w.z, acc[jj].z);
        acc[jj].w = fmaf(av, w.w, acc[jj].w);
      }
    }
  }
  float4 b1v = *(const float4*)&b1[d4];
  __syncthreads();
  #pragma unroll
  for (int jj = 0; jj < 8; ++jj) {
    float4 v = acc[jj];
    v.x = gelu_exact(v.x + b1v.x);
    v.y = gelu_exact(v.y + b1v.y);
    v.z = gelu_exact(v.z + b1v.z);
    v.w = gelu_exact(v.w + b1v.w);
    *(float4*)&s_az[(j8 + jj) * 260 + d4] = v;
  }
  {
    const float4* w2s = (const float4*)W2;
    float4* wdst = (float4*)s_w;
    for (int i = t; i < 2048; i += 256) wdst[i] = w2s[i];
  }
  __syncthreads();
  int j = t >> 3, p4 = (t & 7) * 4;
  float4 o = make_float4(0.f, 0.f, 0.f, 0.f);
  for (int dd = 0; dd < 256; ++dd) {
    float zv = s_az[j * 260 + dd];
    float4 w = *(float4*)&s_w[dd * 32 + p4];
    o.x = fmaf(zv, w.x, o.x);
    o.y = fmaf(zv, w.y, o.y);
    o.z = fmaf(zv, w.z, o.z);
    o.w = fmaf(zv, w.w, o.w);
  }
  float4 b2v = *(const float4*)&b2[p4];
  o.x += b2v.x; o.y += b2v.y; o.z += b2v.z; o.w += b2v.w;
  *(float4*)&out[(size_t)(tok0 + j) * 32 + p4] = o;
}

extern "C" void kernel_launch(void* const* d_in, const int* in_sizes, int n_in,
                              void* d_out, int out_size, void* d_ws, size_t ws_size,
                              hipStream_t stream) {
  const float* y    = (const float*)d_in[0];
  const float* Win  = (const float*)d_in[1];
  const float* bin_ = (const float*)d_in[2];
  const float* ng   = (const float*)d_in[3];
  const float* nb   = (const float*)d_in[4];
  const float* A    = (const float*)d_in[5];
  const float* WB   = (const float*)d_in[6];
  const float* WC   = (const float*)d_in[7];
  const float* qd   = (const float*)d_in[8];
  const float* pd   = (const float*)d_in[9];
  const float* nfg  = (const float*)d_in[10];
  const float* nfb  = (const float*)d_in[11];
  const float* W1   = (const float*)d_in[12];
  const float* b1   = (const float*)d_in[13];
  const float* W2   = (const float*)d_in[14];
  const float* b2   = (const float*)d_in[15];

  float* ws = (float*)d_ws;
  float* hnbuf = ws;                          // NTOK*D; hn -> (in-place) hn2
  float* delta = ws + 4194304;                // NTOK
  float* Bm    = delta + NTOK;                // NTOK*NX
  float* Cm    = Bm + NTOK * NX;              // NTOK*NX
  float* muv   = Cm + NTOK * NX;              // NTOK
  float* irsv  = muv + NTOK;                  // NTOK
  float* Tbuf  = irsv + NTOK;                 // NBATCH*NCH = 512
  float* At    = Tbuf + NBATCH * NCH;         // 4096
  float* EX    = At + D * NX;                 // NBATCH*NCH*D*NX = 2M floats

  k0_at<<<16, 256, 0, stream>>>(A, At);
  k1_front<<<NTOK / 4, 256, 0, stream>>>(y, Win, bin_, ng, nb, WB, WC, qd, pd,
                                         hnbuf, delta, Bm, Cm, muv, irsv);
  k2a_local<<<NBATCH * NCH, 256, 0, stream>>>(hnbuf, delta, Bm, At, EX, Tbuf);
  k2b_chunkscan<<<NBATCH * 16, 256, 0, stream>>>(At, Tbuf, EX);
  k2c_scan2<<<NBATCH * NCH, 256, 0, stream>>>(hnbuf, delta, Bm, Cm, At, EX,
                                              muv, irsv, ng, nb, nfg, nfb,
                                              hnbuf);
  k3b_mlp<<<NTOK / 32, 256, 0, stream>>>(hnbuf, W1, b1, W2, b2, (float*)d_out);
}

// Round 6
// 249.612 us; speedup vs baseline: 1.3694x; 1.1429x over previous
//
#include <hip/hip_runtime.h>
#include <math.h>

#define D 256
#define NX 16
#define L 2048
#define NBATCH 8
#define NTOK (NBATCH * L)
#define CL 32
#define NCH (L / CL)  // 64
#define LOG2E 1.44269504088896340736f

// ---------------- K0: A -> At[n][d] with LOG2E folded ----------------
__global__ __launch_bounds__(256) void k0_at(const float* __restrict__ A,
                                             float* __restrict__ At) {
  int i = blockIdx.x * 256 + threadIdx.x;  // 4096 total
  int d = i >> 4, n = i & 15;
  At[n * D + d] = A[i] * LOG2E;
}

// ---------------- K0b: [WB;WC] -> Wbct[d][c] (c: 0-15 B, 16-31 C) ----------
__global__ __launch_bounds__(256) void k0b_wbct(const float* __restrict__ WB,
                                                const float* __restrict__ WC,
                                                float* __restrict__ Wbct) {
  int i = blockIdx.x * 256 + threadIdx.x;  // 8192 total
  int d = i >> 5, c = i & 31;
  Wbct[i] = (c < 16) ? WB[c * D + d] : WC[(c - 16) * D + d];
}

// ---------------- K1: 32-token block front end (weight-amortized GEMM) ------
// Phase A: h = y@Win+bin (reg tile). LN + delta from regs (wave butterflies).
// Phase C: [Bm|Cm] = hn @ Wbct (reg tile). hn also written to global.
__global__ __launch_bounds__(256) void k1_front(
    const float* __restrict__ y, const float* __restrict__ Win,
    const float* __restrict__ bin_, const float* __restrict__ ng,
    const float* __restrict__ nb, const float* __restrict__ Wbct,
    const float* __restrict__ qd, const float* __restrict__ pd,
    float* __restrict__ hn, float* __restrict__ delta,
    float* __restrict__ Bm, float* __restrict__ Cm,
    float* __restrict__ muv, float* __restrict__ irsv) {
  __shared__ float sy[32][32];    // y tile (reads are wave-uniform broadcasts)
  __shared__ float sh[32][260];   // hn tile, pitch 260 -> phase-C conflict-free
  int t = threadIdx.x;
  int tok0 = blockIdx.x * 32;
  {
    const float4* src = (const float4*)(y + (size_t)tok0 * 32);
    ((float4*)sy)[t] = src[t];  // 1024 floats, fully coalesced
  }
  __syncthreads();
  int dcol = t & 63;          // lane; owns d = dcol*4..+3
  int jrow = t >> 6;          // wave id; wave owns tokens jrow*8..+7
  int d4 = dcol * 4;
  float4 bv = ((const float4*)bin_)[dcol];
  float4 acc[8];
  #pragma unroll
  for (int jj = 0; jj < 8; ++jj) acc[jj] = bv;
  const float4* Win4 = (const float4*)Win;  // [k][64 float4]
  #pragma unroll
  for (int k = 0; k < 32; ++k) {
    float4 wv = Win4[k * 64 + dcol];
    #pragma unroll
    for (int jj = 0; jj < 8; ++jj) {
      float av = sy[jrow * 8 + jj][k];  // wave-uniform broadcast
      acc[jj].x = fmaf(av, wv.x, acc[jj].x);
      acc[jj].y = fmaf(av, wv.y, acc[jj].y);
      acc[jj].z = fmaf(av, wv.z, acc[jj].z);
      acc[jj].w = fmaf(av, wv.w, acc[jj].w);
    }
  }
  // LN + delta per token, straight from registers
  float4 g4 = ((const float4*)ng)[dcol];
  float4 nb4 = ((const float4*)nb)[dcol];
  float4 q4 = ((const float4*)qd)[dcol];
  float pd0 = pd[0];
  #pragma unroll
  for (int jj = 0; jj < 8; ++jj) {
    int j = jrow * 8 + jj;
    int tok = tok0 + j;
    float4 a = acc[jj];
    float s1 = a.x + a.y + a.z + a.w;
    float s2 = a.x * a.x + a.y * a.y + a.z * a.z + a.w * a.w;
    #pragma unroll
    for (int off = 1; off < 64; off <<= 1) {
      s1 += __shfl_xor(s1, off);
      s2 += __shfl_xor(s2, off);
    }
    float mu = s1 * (1.f / D);
    float var = s2 * (1.f / D) - mu * mu;
    float rstd = rsqrtf(var + 1e-5f);
    if (dcol == 0) { muv[tok] = mu; irsv[tok] = sqrtf(var + 1e-5f); }
    float4 v4;
    v4.x = (a.x - mu) * rstd * g4.x + nb4.x;
    v4.y = (a.y - mu) * rstd * g4.y + nb4.y;
    v4.z = (a.z - mu) * rstd * g4.z + nb4.z;
    v4.w = (a.w - mu) * rstd * g4.w + nb4.w;
    ((float4*)(hn + (size_t)tok * D))[dcol] = v4;
    *(float4*)&sh[j][d4] = v4;
    float dd = v4.x * q4.x + v4.y * q4.y + v4.z * q4.z + v4.w * q4.w;
    #pragma unroll
    for (int off = 1; off < 64; off <<= 1) dd += __shfl_xor(dd, off);
    if (dcol == 0) {
      float xx = pd0 + dd;
      delta[tok] = (xx > 20.f) ? xx : log1pf(expf(xx));
    }
  }
  __syncthreads();
  // Phase C: [Bm|Cm](32 tok x 32 cols) = sh(32x256) @ Wbct(256x32)
  int col4 = t & 7;   // float4 column group (cols col4*4..+3)
  int j = t >> 3;     // token 0..31
  const float4* W4 = (const float4*)Wbct;  // [d][8 float4]
  float4 o = make_float4(0.f, 0.f, 0.f, 0.f);
  #pragma unroll 8
  for (int d = 0; d < 256; ++d) {
    float av = sh[j][d];          // 8 j's/wave, banks 4j%32 offset -> no conflict
    float4 w = W4[d * 8 + col4];  // 128 B/wave/step, coalesced
    o.x = fmaf(av, w.x, o.x);
    o.y = fmaf(av, w.y, o.y);
    o.z = fmaf(av, w.z, o.z);
    o.w = fmaf(av, w.w, o.w);
  }
  int tokj = tok0 + j;
  if (col4 < 4) ((float4*)(Bm + (size_t)tokj * NX))[col4] = o;
  else          ((float4*)(Cm + (size_t)tokj * NX))[col4 - 4] = o;
}

// ---------------- K2a: local chunk scans -> end states E only --------------
__global__ __launch_bounds__(256) void k2a_local(
    const float* __restrict__ hn, const float* __restrict__ delta,
    const float* __restrict__ Bm, const float* __restrict__ At,
    float* __restrict__ EX, float* __restrict__ T) {
  __shared__ float shn[CL][D];  // 32 KB
  __shared__ float sB[CL][NX];
  __shared__ float sdelta[CL];
  int ch = blockIdx.x & (NCH - 1);
  int b = blockIdx.x >> 6;
  int t = threadIdx.x;  // = d
  size_t tokbase = (size_t)(b * L + ch * CL);
  if (t < CL) sdelta[t] = delta[tokbase + t];
  for (int i = t; i < CL * NX; i += 256) ((float*)sB)[i] = Bm[tokbase * NX + i];
  {
    const float4* src = (const float4*)(hn + tokbase * D);
    float4* dst = (float4*)shn;
    #pragma unroll
    for (int i = 0; i < 8; ++i) dst[t + 256 * i] = src[t + 256 * i];
  }
  float a16[16];
  #pragma unroll
  for (int n = 0; n < 16; ++n) a16[n] = At[n * D + t];
  __syncthreads();
  if (t < 32) {
    float v = sdelta[t];
    #pragma unroll
    for (int off = 1; off < 32; off <<= 1) v += __shfl_xor(v, off);
    if (t == 0) T[b * NCH + ch] = v;
  }
  float x16[16];
  #pragma unroll
  for (int n = 0; n < 16; ++n) x16[n] = 0.f;
  for (int lo = 0; lo < CL; ++lo) {
    float dlt = sdelta[lo];
    float du = dlt * shn[lo][t];
    #pragma unroll
    for (int n = 0; n < 16; ++n)
      x16[n] = fmaf(exp2f(dlt * a16[n]), x16[n], du * sB[lo][n]);
  }
  size_t exbase = (size_t)blockIdx.x * (NX * D) + t;
  #pragma unroll
  for (int n = 0; n < 16; ++n) EX[exbase + n * D] = x16[n];
}

// ---------------- K2b: chunk-level scan, in-place E -> X, prefetch ---------
__global__ __launch_bounds__(256) void k2b_chunkscan(
    const float* __restrict__ At, const float* __restrict__ T,
    float* __restrict__ EX) {
  __shared__ float sT[NCH];
  int b = blockIdx.x >> 4;
  int rem = ((blockIdx.x & 15) << 8) | threadIdx.x;  // n*D + d
  if (threadIdx.x < NCH) sT[threadIdx.x] = T[b * NCH + threadIdx.x];
  __syncthreads();
  float A2 = At[rem];  // already *LOG2E
  size_t base = ((size_t)b << 18) + rem;
  float eq[4];
  #pragma unroll
  for (int j = 0; j < 4; ++j) eq[j] = EX[base + ((size_t)j << 12)];
  float x = 0.f;
  #pragma unroll 4
  for (int c = 0; c < NCH; ++c) {
    float e = eq[c & 3];
    if (c + 4 < NCH) eq[c & 3] = EX[base + ((size_t)(c + 4) << 12)];
    EX[base + ((size_t)c << 12)] = x;
    x = fmaf(exp2f(sT[c] * A2), x, e);
  }
}

// ---------------- K2c: re-scan with true init state + h recon + LN2 --------
__global__ __launch_bounds__(256) void k2c_scan2(
    const float* __restrict__ hn, const float* __restrict__ delta,
    const float* __restrict__ Bm, const float* __restrict__ Cm,
    const float* __restrict__ At, const float* __restrict__ EX,
    const float* __restrict__ muv, const float* __restrict__ irsv,
    const float* __restrict__ ng, const float* __restrict__ nb,
    const float* __restrict__ nfg, const float* __restrict__ nfb,
    float* __restrict__ hn2) {
  __shared__ float shn[CL][D];
  __shared__ float sB[CL][NX];
  __shared__ float sC[CL][NX];
  __shared__ float sdelta[CL];
  __shared__ float smu[CL];
  __shared__ float sirs[CL];
  int ch = blockIdx.x & (NCH - 1);
  int b = blockIdx.x >> 6;
  int t = threadIdx.x;  // = d
  size_t tokbase = (size_t)(b * L + ch * CL);
  if (t < CL) {
    sdelta[t] = delta[tokbase + t];
    smu[t] = muv[tokbase + t];
    sirs[t] = irsv[tokbase + t];
  }
  for (int i = t; i < CL * NX; i += 256) {
    ((float*)sB)[i] = Bm[tokbase * NX + i];
    ((float*)sC)[i] = Cm[tokbase * NX + i];
  }
  {
    const float4* src = (const float4*)(hn + tokbase * D);
    float4* dst = (float4*)shn;
    #pragma unroll
    for (int i = 0; i < 8; ++i) dst[t + 256 * i] = src[t + 256 * i];
  }
  float a16[16], x16[16];
  size_t exbase = (size_t)blockIdx.x * (NX * D) + t;
  #pragma unroll
  for (int n = 0; n < 16; ++n) {
    a16[n] = At[n * D + t];
    x16[n] = EX[exbase + n * D];
  }
  float nb_d = nb[t];
  float invg = 1.0f / ng[t];
  __syncthreads();
  for (int lo = 0; lo < CL; ++lo) {
    float dlt = sdelta[lo];
    float hv = shn[lo][t];
    float du = dlt * hv;
    float p = 0.f;
    #pragma unroll
    for (int n = 0; n < 16; ++n) {
      x16[n] = fmaf(exp2f(dlt * a16[n]), x16[n], du * sB[lo][n]);
      p = fmaf(x16[n], sC[lo][n], p);
    }
    float h = fmaf((hv - nb_d) * invg, sirs[lo], smu[lo]);
    shn[lo][t] = h + p;
  }
  __syncthreads();
  int w = t >> 6, lane = t & 63;
  float4 g4 = ((const float4*)nfg)[lane];
  float4 b4 = ((const float4*)nfb)[lane];
  for (int j = 0; j < 8; ++j) {
    int lo = w * 8 + j;
    float4 v = *(float4*)&shn[lo][lane * 4];
    float s1 = v.x + v.y + v.z + v.w;
    float s2 = v.x * v.x + v.y * v.y + v.z * v.z + v.w * v.w;
    #pragma unroll
    for (int off = 1; off < 64; off <<= 1) {
      s1 += __shfl_xor(s1, off);
      s2 += __shfl_xor(s2, off);
    }
    float mu2 = s1 * (1.f / D);
    float var2 = s2 * (1.f / D) - mu2 * mu2;
    float rstd2 = rsqrtf(var2 + 1e-5f);
    float4 o;
    o.x = (v.x - mu2) * rstd2 * g4.x + b4.x;
    o.y = (v.y - mu2) * rstd2 * g4.y + b4.y;
    o.z = (v.z - mu2) * rstd2 * g4.z + b4.z;
    o.w = (v.w - mu2) * rstd2 * g4.w + b4.w;
    ((float4*)(hn2 + (tokbase + lo) * D))[lane] = o;
  }
}

__device__ __forceinline__ float gelu_exact(float x) {
  return 0.5f * x * (1.f + erff(x * 0.70710678118654752440f));
}

// ---------------- K3b: MLP (unchanged) --------------------------------------
__global__ __launch_bounds__(256) void k3b_mlp(
    const float* __restrict__ hn2, const float* __restrict__ W1,
    const float* __restrict__ b1, const float* __restrict__ W2,
    const float* __restrict__ b2, float* __restrict__ out) {
  __shared__ float s_az[32 * 260];
  __shared__ float s_w[32 * 256];
  int t = threadIdx.x;
  int tok0 = blockIdx.x * 32;
  {
    const float4* src = (const float4*)(hn2 + (size_t)tok0 * D);
    float4* dst = (float4*)s_az;
    for (int i = t; i < 2048; i += 256) dst[i] = src[i];
  }
  float4 acc[8];
  #pragma unroll
  for (int jj = 0; jj < 8; ++jj) acc[jj] = make_float4(0.f, 0.f, 0.f, 0.f);
  int dcol = t & 63, jrow = t >> 6;
  int d4 = dcol * 4, j8 = jrow * 8;
  for (int kb = 0; kb < 256; kb += 32) {
    __syncthreads();
    {
      const float4* wsrc = (const float4*)(W1 + kb * D);
      float4* wdst = (float4*)s_w;
      for (int i = t; i < 2048; i += 256) wdst[i] = wsrc[i];
    }
    __syncthreads();
    #pragma unroll 8
    for (int k = 0; k < 32; ++k) {
      float4 w = *(float4*)&s_w[k * D + d4];
      #pragma unroll
      for (int jj = 0; jj < 8; ++jj) {
        float av = s_az[(j8 + jj) * 256 + kb + k];
        acc[jj].x = fmaf(av, w.x, acc[jj].x);
        acc[jj].y = fmaf(av, w.y, acc[jj].y);
        acc[jj].z = fmaf(av, w.z, acc[jj].z);
        acc[jj].w = fmaf(av, w.w, acc[jj].w);
      }
    }
  }
  float4 b1v = *(const float4*)&b1[d4];
  __syncthreads();
  #pragma unroll
  for (int jj = 0; jj < 8; ++jj) {
    float4 v = acc[jj];
    v.x = gelu_exact(v.x + b1v.x);
    v.y = gelu_exact(v.y + b1v.y);
    v.z = gelu_exact(v.z + b1v.z);
    v.w = gelu_exact(v.w + b1v.w);
    *(float4*)&s_az[(j8 + jj) * 260 + d4] = v;
  }
  {
    const float4* w2s = (const float4*)W2;
    float4* wdst = (float4*)s_w;
    for (int i = t; i < 2048; i += 256) wdst[i] = w2s[i];
  }
  __syncthreads();
  int j = t >> 3, p4 = (t & 7) * 4;
  float4 o = make_float4(0.f, 0.f, 0.f, 0.f);
  for (int dd = 0; dd < 256; ++dd) {
    float zv = s_az[j * 260 + dd];
    float4 w = *(float4*)&s_w[dd * 32 + p4];
    o.x = fmaf(zv, w.x, o.x);
    o.y = fmaf(zv, w.y, o.y);
    o.z = fmaf(zv, w.z, o.z);
    o.w = fmaf(zv, w.w, o.w);
  }
  float4 b2v = *(const float4*)&b2[p4];
  o.x += b2v.x; o.y += b2v.y; o.z += b2v.z; o.w += b2v.w;
  *(float4*)&out[(size_t)(tok0 + j) * 32 + p4] = o;
}

extern "C" void kernel_launch(void* const* d_in, const int* in_sizes, int n_in,
                              void* d_out, int out_size, void* d_ws, size_t ws_size,
                              hipStream_t stream) {
  const float* y    = (const float*)d_in[0];
  const float* Win  = (const float*)d_in[1];
  const float* bin_ = (const float*)d_in[2];
  const float* ng   = (const float*)d_in[3];
  const float* nb   = (const float*)d_in[4];
  const float* A    = (const float*)d_in[5];
  const float* WB   = (const float*)d_in[6];
  const float* WC   = (const float*)d_in[7];
  const float* qd   = (const float*)d_in[8];
  const float* pd   = (const float*)d_in[9];
  const float* nfg  = (const float*)d_in[10];
  const float* nfb  = (const float*)d_in[11];
  const float* W1   = (const float*)d_in[12];
  const float* b1   = (const float*)d_in[13];
  const float* W2   = (const float*)d_in[14];
  const float* b2   = (const float*)d_in[15];

  float* ws = (float*)d_ws;
  float* hnbuf = ws;                          // NTOK*D; hn -> (in-place) hn2
  float* delta = ws + 4194304;                // NTOK
  float* Bm    = delta + NTOK;                // NTOK*NX
  float* Cm    = Bm + NTOK * NX;              // NTOK*NX
  float* muv   = Cm + NTOK * NX;              // NTOK
  float* irsv  = muv + NTOK;                  // NTOK
  float* Tbuf  = irsv + NTOK;                 // NBATCH*NCH = 512
  float* At    = Tbuf + NBATCH * NCH;         // 4096
  float* Wbct  = At + D * NX;                 // 8192
  float* EX    = Wbct + D * 32;               // NBATCH*NCH*D*NX = 2M floats

  k0_at<<<16, 256, 0, stream>>>(A, At);
  k0b_wbct<<<32, 256, 0, stream>>>(WB, WC, Wbct);
  k1_front<<<NTOK / 32, 256, 0, stream>>>(y, Win, bin_, ng, nb, Wbct, qd, pd,
                                          hnbuf, delta, Bm, Cm, muv, irsv);
  k2a_local<<<NBATCH * NCH, 256, 0, stream>>>(hnbuf, delta, Bm, At, EX, Tbuf);
  k2b_chunkscan<<<NBATCH * 16, 256, 0, stream>>>(At, Tbuf, EX);
  k2c_scan2<<<NBATCH * NCH, 256, 0, stream>>>(hnbuf, delta, Bm, Cm, At, EX,
                                              muv, irsv, ng, nb, nfg, nfb,
                                              hnbuf);
  k3b_mlp<<<NTOK / 32, 256, 0, stream>>>(hnbuf, W1, b1, W2, b2, (float*)d_out);
}